// Round 6
// baseline (120.038 us; speedup 1.0000x reference)
//
#include <hip/hip_runtime.h>
#include <stdint.h>

// ---------------- problem constants ----------------
#define B_ROWS 16384
#define NF 26
#define NV 100000
#define ND 13
#define NH 400
#define XPAD 448     // GEMM1 K padded (14 tiles of 32)
#define ZPAD 416     // GEMM2 K padded (13 tiles of 32)
#define EPS 1e-5f

typedef __attribute__((ext_vector_type(8))) short short8;
typedef __attribute__((ext_vector_type(4))) float f32x4;
typedef __attribute__((ext_vector_type(4))) unsigned int uint4v;

__device__ inline float bf2f(unsigned short u) {
    union { unsigned int i; float f; } v; v.i = (unsigned int)u << 16; return v.f;
}
__device__ inline unsigned short f2bf(float f) {
    union { float f; unsigned int i; } v; v.f = f;
    unsigned int r = (v.i + 0x7fff + ((v.i >> 16) & 1)) >> 16;
    return (unsigned short)r;
}

// direct global->LDS DMA, 16B/lane; lds dest = wave-uniform base + lane*16
typedef __attribute__((address_space(1))) const unsigned int g_u32;
typedef __attribute__((address_space(3))) unsigned int l_u32;
__device__ __forceinline__ void gload_lds16(const void* g, void* l) {
    __builtin_amdgcn_global_load_lds((g_u32*)g, (l_u32*)l, 16, 0, 0);
}

// ---------------- ws layout (bytes) ----------------
// Z1 : bf16 [16384][416] ; Z2 : bf16 [16384][416]
// W1s: staged [14][4][448][8] ; W2s: staged [13][4][448][8]
#define Z1_OFF   0
#define Z2_OFF   13631488
#define W1S_OFF  27262976
#define W2S_OFF  27664384
#define BASE_OFF 28037120
#define ST_OFF   28102656

// =====================================================================
// prep: W [K][400] f32 -> staged bf16 [NT][4][448][8]; zero stats.
// element (kt,q,n,j) = W[kt*32+q*8+j][n]  (zero-padded)
// =====================================================================
__global__ __launch_bounds__(512) void prep_w(
    const float* __restrict__ W1, const float* __restrict__ W2,
    unsigned short* __restrict__ W1s, unsigned short* __restrict__ W2s,
    float* __restrict__ st)
{
    int c = blockIdx.x * 512 + threadIdx.x;
    if (blockIdx.x == 0) {
        for (int i = threadIdx.x; i < 1664; i += 512) st[i] = 0.f;
    }
    if (c >= 48384) return;
    const float* W; unsigned short* dst; int K; int cc;
    if (c < 25088) { W = W1; dst = W1s; K = 429; cc = c; }
    else           { W = W2; dst = W2s; K = 400; cc = c - 25088; }
    int n  = cc % 448;
    int q  = (cc / 448) & 3;
    int kt = cc / 1792;
    unsigned short o[8];
    #pragma unroll
    for (int j = 0; j < 8; ++j) {
        int k = kt * 32 + q * 8 + j;
        float v = (n < NH && k < K) ? W[(size_t)k * NH + n] : 0.f;
        o[j] = f2bf(v);
    }
    *(uint4v*)(dst + (size_t)cc * 8) = *(uint4v*)o;
}

// =====================================================================
// K1: fused gather + FM + GEMM1.  grid = 256 x 512.
// Wave wv: rows (wv&3)*16+l15, N-half (wv>>2).  Lane (qh,l15) gathers its
// own A-fragments for all 14 K-tiles up-front (13 random emb loads + dense),
// computes FM stats in fp32, converts to bf16 fr[14], then runs the K-loop
// with W double-buffered via global_load_lds (waves 0..6 stage).
// =====================================================================
__global__ __launch_bounds__(512, 4) void gemm1_fused(
    const int* __restrict__ Xcat, const float* __restrict__ Xd,
    const float* __restrict__ fm1, const float* __restrict__ emb,
    const float* __restrict__ Wd, const float* __restrict__ bd,
    const unsigned short* __restrict__ Wst, const float* __restrict__ bias,
    unsigned short* __restrict__ Z, float* __restrict__ base,
    float* __restrict__ gsum, float* __restrict__ gsq)
{
    __shared__ unsigned short b_s[2][14336];      // 57,344 B
    __shared__ float sredS[4][416];               // 6,656 B
    __shared__ float sredQ[4][416];               // 6,656 B

    const int tid = threadIdx.x;
    const int lane = tid & 63;
    const int wv = tid >> 6;
    const int rowgrp = wv & 3;
    const int nhalf = wv >> 2;
    const int l15 = lane & 15;
    const int qh = lane >> 4;
    const int m0 = blockIdx.x * 64;
    const int arow = m0 + rowgrp * 16 + l15;
    const int c0 = nhalf * 208;
    const int NFRAG = nhalf ? 12 : 13;

    auto stage = [&](int kt, int buf) {
        #pragma unroll
        for (int i = 0; i < 4; ++i) {
            int cchunk = wv * 256 + i * 64 + lane;
            gload_lds16(Wst + (size_t)kt * 14336 + (size_t)cchunk * 8,
                        &b_s[buf][(size_t)(wv * 256 + i * 64) * 8]);
        }
    };
    if (wv < 7) stage(0, 0);     // W tile 0 DMA flies under the gather

    const int* idxp = Xcat + (size_t)arow * NF;
    const int fpar = qh >> 1;            // field parity
    const int khalf = (qh & 1) << 3;     // k-offset 0 or 8

    short8 fr[14];
    float s8[8] = {0.f,0.f,0.f,0.f,0.f,0.f,0.f,0.f};
    float ssacc = 0.f;
    float dsum = 0.f;

    // ---- batch 1: emb tiles 0..6 (7 x 32B random loads, all in flight) ----
    {
        float v[7][8];
        #pragma unroll
        for (int kt = 0; kt < 7; ++kt) {
            int f = 2 * kt + fpar;
            int idx = idxp[f];
            const float* p = emb + (((size_t)f * NV + (size_t)idx) << 4) + khalf;
            f32x4 x0 = *(const f32x4*)p;
            f32x4 x1 = *(const f32x4*)(p + 4);
            v[kt][0]=x0[0]; v[kt][1]=x0[1]; v[kt][2]=x0[2]; v[kt][3]=x0[3];
            v[kt][4]=x1[0]; v[kt][5]=x1[1]; v[kt][6]=x1[2]; v[kt][7]=x1[3];
        }
        #pragma unroll
        for (int kt = 0; kt < 7; ++kt) {
            if (nhalf == 0) {
                #pragma unroll
                for (int j = 0; j < 8; ++j) { s8[j] += v[kt][j]; ssacc += v[kt][j]*v[kt][j]; }
            }
            #pragma unroll
            for (int j = 0; j < 8; ++j) fr[kt][j] = (short)f2bf(v[kt][j]);
        }
    }
    // ---- batch 2: emb tiles 7..12 + dense tile 13 ----
    {
        float v[7][8];
        #pragma unroll
        for (int kt = 7; kt < 13; ++kt) {
            int f = 2 * kt + fpar;
            int idx = idxp[f];
            const float* p = emb + (((size_t)f * NV + (size_t)idx) << 4) + khalf;
            f32x4 x0 = *(const f32x4*)p;
            f32x4 x1 = *(const f32x4*)(p + 4);
            v[kt-7][0]=x0[0]; v[kt-7][1]=x0[1]; v[kt-7][2]=x0[2]; v[kt-7][3]=x0[3];
            v[kt-7][4]=x1[0]; v[kt-7][5]=x1[1]; v[kt-7][6]=x1[2]; v[kt-7][7]=x1[3];
        }
        #pragma unroll
        for (int j = 0; j < 8; ++j) {
            int cd = khalf + j;
            v[6][j] = (qh < 2 && cd < ND) ? Xd[(size_t)arow * ND + cd] : 0.f;
        }
        #pragma unroll
        for (int kt = 7; kt < 13; ++kt) {
            if (nhalf == 0) {
                #pragma unroll
                for (int j = 0; j < 8; ++j) { s8[j] += v[kt-7][j]; ssacc += v[kt-7][j]*v[kt-7][j]; }
            }
            #pragma unroll
            for (int j = 0; j < 8; ++j) fr[kt][j] = (short)f2bf(v[kt-7][j]);
        }
        #pragma unroll
        for (int j = 0; j < 8; ++j) fr[13][j] = (short)f2bf(v[6][j]);
        if (nhalf == 0 && qh < 2) {
            #pragma unroll
            for (int j = 0; j < 8; ++j) {
                int cd = khalf + j;
                if (cd < ND) dsum += v[6][j] * Wd[cd];
            }
        }
    }
    // ---- FM 1st order ----
    float fmsum = 0.f;
    if (nhalf == 0) {
        for (int f = qh; f < NF; f += 4)
            fmsum += fm1[(size_t)f * NV + idxp[f]];
    }

    f32x4 acc[13];
    #pragma unroll
    for (int i = 0; i < 13; ++i) acc[i] = f32x4{0.f, 0.f, 0.f, 0.f};

    __syncthreads();    // tile 0 staged (barrier drains vmcnt)

    // ---- K-loop: zero A-traffic, W dbuf DMA ----
    #pragma unroll
    for (int kt = 0; kt < 14; ++kt) {
        if (kt + 1 < 14 && wv < 7) stage(kt + 1, (kt + 1) & 1);
        const unsigned short* bb = &b_s[kt & 1][(size_t)(qh * 448 + c0 + l15) * 8];
        #pragma unroll
        for (int nn = 0; nn < 13; ++nn) {
            if (nn < NFRAG) {
                short8 bf = *(const short8*)(bb + nn * 128);
                acc[nn] = __builtin_amdgcn_mfma_f32_16x16x32_bf16(fr[kt], bf, acc[nn], 0, 0, 0);
            }
        }
        __syncthreads();
    }

    // ---- FM base write (cross-qh reduce; verified mapping from R4) ----
    if (nhalf == 0) {
        float red = 0.f;
        #pragma unroll
        for (int j = 0; j < 8; ++j) {
            float sf = s8[j] + __shfl_xor(s8[j], 32, 64);
            red += sf * sf;
        }
        red -= (ssacc + __shfl_xor(ssacc, 32, 64));
        red += __shfl_xor(red, 16, 64);
        float fr2 = fmsum + __shfl_xor(fmsum, 16, 64);
        fr2 += __shfl_xor(fr2, 32, 64);
        float dr = dsum + __shfl_xor(dsum, 16, 64);
        dr += __shfl_xor(dr, 32, 64);
        if (qh == 0) base[arow] = 0.5f * red + fr2 + dr + bd[0];
    }

    // ---- epilogue: +bias, bf16 store, fp32 column stats ----
    #pragma unroll
    for (int nn = 0; nn < 13; ++nn) {
        if (nn < NFRAG) {
            int col = c0 + nn * 16 + l15;
            float bv = bias[col];
            float ps = 0.f, pq = 0.f;
            #pragma unroll
            for (int q = 0; q < 4; ++q) {
                float v = acc[nn][q] + bv;
                ps += v; pq += v * v;
                Z[(size_t)(m0 + rowgrp * 16 + qh * 4 + q) * ZPAD + col] = f2bf(v);
            }
            ps += __shfl_xor(ps, 16, 64); ps += __shfl_xor(ps, 32, 64);
            pq += __shfl_xor(pq, 16, 64); pq += __shfl_xor(pq, 32, 64);
            if (lane < 16) { sredS[rowgrp][col] = ps; sredQ[rowgrp][col] = pq; }
        }
    }
    if (nhalf == 1) {   // zero-pad cols 400..415 for GEMM2's A reads
        int col = NH + l15;
        #pragma unroll
        for (int q = 0; q < 4; ++q)
            Z[(size_t)(m0 + rowgrp * 16 + qh * 4 + q) * ZPAD + col] = 0;
    }
    __syncthreads();
    for (int c = tid; c < NH; c += 512) {
        float s = sredS[0][c] + sredS[1][c] + sredS[2][c] + sredS[3][c];
        float q = sredQ[0][c] + sredQ[1][c] + sredQ[2][c] + sredQ[3][c];
        atomicAdd(&gsum[c], s);
        atomicAdd(&gsq[c], q);
    }
}

// =====================================================================
// K2: MFMA GEMM with fused BN1+ReLU on A, 2-phase gload_lds W staging.
// =====================================================================
__global__ __launch_bounds__(512, 2) void mfma_gemm2(
    const unsigned short* __restrict__ A,
    const unsigned short* __restrict__ Wst,
    const float* __restrict__ bias,
    const float* __restrict__ gsumIn, const float* __restrict__ gsqIn,
    const float* __restrict__ g, const float* __restrict__ be,
    unsigned short* __restrict__ Z,
    float* __restrict__ gsum, float* __restrict__ gsq)
{
    __shared__ unsigned short b_s[2][14336];
    __shared__ float sredS[4][416];
    __shared__ float sredQ[4][416];
    __shared__ float alpha_s[416], beta_s[416];

    const int tid = threadIdx.x;
    const int lane = tid & 63;
    const int wv = tid >> 6;
    const int rowgrp = wv & 3;
    const int nhalf = wv >> 2;
    const int l15 = lane & 15;
    const int qh = lane >> 4;
    const int m0 = blockIdx.x * 64;
    const int arow = m0 + rowgrp * 16 + l15;
    const int c0 = nhalf * 208;
    const int NFRAG = nhalf ? 12 : 13;

    for (int c = tid; c < ZPAD; c += 512) {
        float a = 0.f, b = 0.f;
        if (c < NH) {
            float mean = gsumIn[c] * (1.f / B_ROWS);
            float var  = gsqIn[c] * (1.f / B_ROWS) - mean * mean;
            a = g[c] * rsqrtf(var + EPS);
            b = be[c] - mean * a;
        }
        alpha_s[c] = a; beta_s[c] = b;
    }

    f32x4 acc[13];
    #pragma unroll
    for (int i = 0; i < 13; ++i) acc[i] = f32x4{0.f, 0.f, 0.f, 0.f};

    auto stage = [&](int kt, int buf) {
        #pragma unroll
        for (int i = 0; i < 4; ++i) {
            int cchunk = wv * 256 + i * 64 + lane;
            gload_lds16(Wst + (size_t)kt * 14336 + (size_t)cchunk * 8,
                        &b_s[buf][(size_t)(wv * 256 + i * 64) * 8]);
        }
    };

    if (wv < 7) stage(0, 0);
    short8 af_next = *(const short8*)(A + (size_t)arow * ZPAD + qh * 8);
    __syncthreads();

    for (int kt = 0; kt < 13; ++kt) {
        if (kt + 1 < 13 && wv < 7) stage(kt + 1, (kt + 1) & 1);
        short8 af = af_next;
        if (kt + 1 < 13)
            af_next = *(const short8*)(A + (size_t)arow * ZPAD + (kt + 1) * 32 + qh * 8);
        int k0 = kt * 32 + qh * 8;
        #pragma unroll
        for (int j = 0; j < 8; ++j) {
            float f = bf2f((unsigned short)af[j]);
            f = fmaxf(0.f, alpha_s[k0 + j] * f + beta_s[k0 + j]);
            af[j] = (short)f2bf(f);
        }
        const unsigned short* bb = &b_s[kt & 1][(size_t)(qh * 448 + c0 + l15) * 8];
        #pragma unroll
        for (int nn = 0; nn < 13; ++nn) {
            if (nn < NFRAG) {
                short8 bf = *(const short8*)(bb + nn * 128);
                acc[nn] = __builtin_amdgcn_mfma_f32_16x16x32_bf16(af, bf, acc[nn], 0, 0, 0);
            }
        }
        __syncthreads();
    }

    #pragma unroll
    for (int nn = 0; nn < 13; ++nn) {
        if (nn < NFRAG) {
            int col = c0 + nn * 16 + l15;
            float bv = bias[col];
            float ps = 0.f, pq = 0.f;
            #pragma unroll
            for (int q = 0; q < 4; ++q) {
                float v = acc[nn][q] + bv;
                ps += v; pq += v * v;
                Z[(size_t)(m0 + rowgrp * 16 + qh * 4 + q) * ZPAD + col] = f2bf(v);
            }
            ps += __shfl_xor(ps, 16, 64); ps += __shfl_xor(ps, 32, 64);
            pq += __shfl_xor(pq, 16, 64); pq += __shfl_xor(pq, 32, 64);
            if (lane < 16) { sredS[rowgrp][col] = ps; sredQ[rowgrp][col] = pq; }
        }
    }
    __syncthreads();
    for (int c = tid; c < NH; c += 512) {
        float s = sredS[0][c] + sredS[1][c] + sredS[2][c] + sredS[3][c];
        float q = sredQ[0][c] + sredQ[1][c] + sredQ[2][c] + sredQ[3][c];
        atomicAdd(&gsum[c], s);
        atomicAdd(&gsq[c], q);
    }
}

// =====================================================================
// final: finalize BN2 in-block, then out[r] = base[r] + relu(.)·W3 + b3
// =====================================================================
__global__ __launch_bounds__(256) void final_kernel(
    const unsigned short* __restrict__ Z2,
    const float* __restrict__ gsum2, const float* __restrict__ gsq2,
    const float* __restrict__ g2, const float* __restrict__ be2,
    const float* __restrict__ W3, const float* __restrict__ b3,
    const float* __restrict__ base, float* __restrict__ out)
{
    __shared__ float a2s[NH], b2s[NH], w3s[NH];
    int tid = threadIdx.x;
    for (int c = tid; c < NH; c += 256) {
        float mean = gsum2[c] * (1.f / B_ROWS);
        float var  = gsq2[c] * (1.f / B_ROWS) - mean * mean;
        float a = g2[c] * rsqrtf(var + EPS);
        a2s[c] = a;
        b2s[c] = be2[c] - mean * a;
        w3s[c] = W3[c];
    }
    __syncthreads();
    int lane = tid & 63;
    int wv = tid >> 6;
    bool act = lane < 50;
    int cb = lane * 8;
    float al[8], bb[8], w3[8];
    #pragma unroll
    for (int j = 0; j < 8; ++j) {
        al[j] = act ? a2s[cb + j] : 0.f;
        bb[j] = act ? b2s[cb + j] : 0.f;
        w3[j] = act ? w3s[cb + j] : 0.f;
    }
    int r0 = blockIdx.x * 32 + wv * 8;
    float bias3 = b3[0];
    for (int t = 0; t < 8; t += 2) {
        int r = r0 + t;
        float acc0 = 0.f, acc1 = 0.f;
        if (act) {
            short8 z0 = *(const short8*)(Z2 + (size_t)r * ZPAD + cb);
            short8 z1 = *(const short8*)(Z2 + (size_t)(r + 1) * ZPAD + cb);
            #pragma unroll
            for (int j = 0; j < 8; ++j) {
                acc0 += fmaxf(0.f, al[j] * bf2f((unsigned short)z0[j]) + bb[j]) * w3[j];
                acc1 += fmaxf(0.f, al[j] * bf2f((unsigned short)z1[j]) + bb[j]) * w3[j];
            }
        }
        #pragma unroll
        for (int off = 32; off; off >>= 1) {
            acc0 += __shfl_xor(acc0, off, 64);
            acc1 += __shfl_xor(acc1, off, 64);
        }
        if (lane == 0) out[r] = base[r] + acc0 + bias3;
        if (lane == 1) out[r + 1] = base[r + 1] + acc1 + bias3;
    }
}

// =====================================================================
extern "C" void kernel_launch(void* const* d_in, const int* in_sizes, int n_in,
                              void* d_out, int out_size, void* d_ws, size_t ws_size,
                              hipStream_t stream)
{
    const int*   Xcat = (const int*)d_in[0];
    const float* Xd   = (const float*)d_in[1];
    const float* fm1  = (const float*)d_in[2];
    const float* emb  = (const float*)d_in[3];
    const float* Wd   = (const float*)d_in[4];
    const float* bd   = (const float*)d_in[5];
    const float* W1   = (const float*)d_in[6];
    const float* b1   = (const float*)d_in[7];
    const float* g1   = (const float*)d_in[8];
    const float* be1  = (const float*)d_in[9];
    const float* W2   = (const float*)d_in[10];
    const float* b2   = (const float*)d_in[11];
    const float* g2   = (const float*)d_in[12];
    const float* be2  = (const float*)d_in[13];
    const float* W3   = (const float*)d_in[14];
    const float* b3   = (const float*)d_in[15];

    char* ws = (char*)d_ws;
    unsigned short* Z1  = (unsigned short*)(ws + Z1_OFF);
    unsigned short* Z2  = (unsigned short*)(ws + Z2_OFF);
    unsigned short* W1s = (unsigned short*)(ws + W1S_OFF);
    unsigned short* W2s = (unsigned short*)(ws + W2S_OFF);
    float* base = (float*)(ws + BASE_OFF);
    float* st   = (float*)(ws + ST_OFF);
    float* gsum1 = st;          float* gsq1 = st + 416;
    float* gsum2 = st + 832;    float* gsq2 = st + 1248;
    float* out = (float*)d_out;

    // 1: stage W1/W2 + zero stats (48384 chunks)
    prep_w<<<95, 512, 0, stream>>>(W1, W2, W1s, W2s, st);

    // 2: fused gather + FM + GEMM1
    gemm1_fused<<<256, 512, 0, stream>>>(Xcat, Xd, fm1, emb, Wd, bd,
                                         W1s, b1, Z1, base, gsum1, gsq1);

    // 3: Z2 = relu(bn1(Z1)) @ W2 + b2, stats2
    mfma_gemm2<<<256, 512, 0, stream>>>(Z1, W2s, b2, gsum1, gsq1, g1, be1,
                                        Z2, gsum2, gsq2);

    // 4: out = base + relu(bn2(Z2))·W3 + b3
    final_kernel<<<512, 256, 0, stream>>>(Z2, gsum2, gsq2, g2, be2, W3, b3, base, out);
}

// Round 7
// 80.173 us; speedup vs baseline: 1.4972x; 1.4972x over previous
//
#include <hip/hip_runtime.h>
#include <stdint.h>

// ---------------- problem constants ----------------
#define B_ROWS 16384
#define NF 26
#define NV 100000
#define ND 13
#define NH 400
#define ZPAD 416     // GEMM K padded (13 tiles of 32)
#define EPS 1e-5f

typedef __attribute__((ext_vector_type(8))) short short8;
typedef __attribute__((ext_vector_type(4))) float f32x4;
typedef __attribute__((ext_vector_type(4))) unsigned int uint4v;

__device__ inline float bf2f(unsigned short u) {
    union { unsigned int i; float f; } v; v.i = (unsigned int)u << 16; return v.f;
}
__device__ inline unsigned short f2bf(float f) {
    union { float f; unsigned int i; } v; v.f = f;
    unsigned int r = (v.i + 0x7fff + ((v.i >> 16) & 1)) >> 16;
    return (unsigned short)r;
}

// direct global->LDS DMA, 16B/lane; lds dest = wave-uniform base + lane*16
typedef __attribute__((address_space(1))) const unsigned int g_u32;
typedef __attribute__((address_space(3))) unsigned int l_u32;
__device__ __forceinline__ void gload_lds16(const void* g, void* l) {
    __builtin_amdgcn_global_load_lds((g_u32*)g, (l_u32*)l, 16, 0, 0);
}

// ---------------- ws layout (bytes) ----------------
#define Z1_OFF   0
#define Z2_OFF   13631488
#define W1S_OFF  27262976
#define W2S_OFF  27664384
#define BASE_OFF 28037120
#define ST_OFF   28102656

// =====================================================================
// prep: W [K][400] f32 -> staged bf16 [NT][4][448][8]; zero stats.
// element (kt,q,n,j) = W[kt*32+q*8+j][n]  (zero-padded)
// =====================================================================
__global__ __launch_bounds__(512) void prep_w(
    const float* __restrict__ W1, const float* __restrict__ W2,
    unsigned short* __restrict__ W1s, unsigned short* __restrict__ W2s,
    float* __restrict__ st)
{
    int c = blockIdx.x * 512 + threadIdx.x;
    if (blockIdx.x == 0) {
        for (int i = threadIdx.x; i < 1664; i += 512) st[i] = 0.f;
    }
    if (c >= 48384) return;
    const float* W; unsigned short* dst; int K; int cc;
    if (c < 25088) { W = W1; dst = W1s; K = 429; cc = c; }
    else           { W = W2; dst = W2s; K = 400; cc = c - 25088; }
    int n  = cc % 448;
    int q  = (cc / 448) & 3;
    int kt = cc / 1792;
    unsigned short o[8];
    #pragma unroll
    for (int j = 0; j < 8; ++j) {
        int k = kt * 32 + q * 8 + j;
        float v = (n < NH && k < K) ? W[(size_t)k * NH + n] : 0.f;
        o[j] = f2bf(v);
    }
    *(uint4v*)(dst + (size_t)cc * 8) = *(uint4v*)o;
}

// =====================================================================
// K1: fused gather + FM + GEMM1.  grid = 256 x 512, 1 block/CU.
// Phase A: wave wv (rowgrp=wv&3, th=wv>>2) gathers A-frags for tiles
//   th*7..th*7+6 (th=1: 6 emb tiles; dense tile built in regs by all),
//   rows rowgrp*16+l15, into shared a_s; FM partials -> LDS.
// FM reduce: 8 threads/row after barrier.
// Phase B: K-loop, A from LDS (zero global A-traffic), W dbuf DMA.
// =====================================================================
__global__ __launch_bounds__(512, 2) void gemm1_fused(
    const int* __restrict__ Xcat, const float* __restrict__ Xd,
    const float* __restrict__ fm1, const float* __restrict__ emb,
    const float* __restrict__ Wd, const float* __restrict__ bd,
    const unsigned short* __restrict__ Wst, const float* __restrict__ bias,
    unsigned short* __restrict__ Z, float* __restrict__ base,
    float* __restrict__ gsum, float* __restrict__ gsq)
{
    __shared__ unsigned short b_s[2][14336];          // 57,344 B  W dbuf
    __shared__ unsigned short a_s[13 * 4 * 64 * 8];   // 53,248 B  A frags [kt][qh][row]
    __shared__ union {
        struct {
            float sfm[2][64][4][8];   // th x row x qh x j   partial sums
            float ssq[2][64][4];      // sum of squares partials
            float fmp[64][4];         // fm1 partials (th=0)
            float dsp[64][2];         // dense-dot partials (th=1, qh<2)
        } gat;                        // 19,968 B
        struct { float S[4][416]; float Q[4][416]; } red;   // 13,312 B
    } u;                                               // 19,968 B
    // total LDS = 130,560 B -> 1 block/CU

    const int tid = threadIdx.x;
    const int lane = tid & 63;
    const int wv = tid >> 6;
    const int rowgrp = wv & 3;
    const int nhalf = wv >> 2;            // doubles as tile-half "th"
    const int l15 = lane & 15;
    const int qh = lane >> 4;
    const int m0 = blockIdx.x * 64;
    const int rloc = rowgrp * 16 + l15;
    const int arow = m0 + rloc;
    const int c0 = nhalf * 208;
    const int NFRAG = nhalf ? 12 : 13;

    auto stage = [&](int kt, int buf) {
        #pragma unroll
        for (int i = 0; i < 4; ++i) {
            int cchunk = wv * 256 + i * 64 + lane;
            gload_lds16(Wst + (size_t)kt * 14336 + (size_t)cchunk * 8,
                        &b_s[buf][(size_t)(wv * 256 + i * 64) * 8]);
        }
    };
    if (wv < 7) stage(0, 0);     // W tile 0 DMA flies under the gather

    const int* idxp = Xcat + (size_t)arow * NF;
    const int fpar = qh >> 1;
    const int khalf = (qh & 1) << 3;
    const int tbase = nhalf * 7;
    const int ntile = nhalf ? 6 : 7;      // th=1's 7th slot is the dense tile

    // ---- gather: up to 7 independent random 32B loads, all in flight ----
    float v[7][8];
    #pragma unroll
    for (int t = 0; t < 7; ++t) {
        if (t < ntile) {
            int f = 2 * (tbase + t) + fpar;
            int idx = idxp[f];
            const float* p = emb + (((size_t)f * NV + (size_t)idx) << 4) + khalf;
            f32x4 x0 = *(const f32x4*)p;
            f32x4 x1 = *(const f32x4*)(p + 4);
            v[t][0]=x0[0]; v[t][1]=x0[1]; v[t][2]=x0[2]; v[t][3]=x0[3];
            v[t][4]=x1[0]; v[t][5]=x1[1]; v[t][6]=x1[2]; v[t][7]=x1[3];
        }
    }
    // dense fragment (kt=13) in regs, every wave
    short8 af13;
    {
        float dv[8];
        #pragma unroll
        for (int j = 0; j < 8; ++j) {
            int cd = khalf + j;
            float x = (qh < 2 && cd < ND) ? Xd[(size_t)arow * ND + cd] : 0.f;
            dv[j] = x;
            af13[j] = (short)f2bf(x);
        }
        if (nhalf == 1 && qh < 2) {
            float ds = 0.f;
            #pragma unroll
            for (int j = 0; j < 8; ++j) {
                int cd = khalf + j;
                if (cd < ND) ds += dv[j] * Wd[cd];
            }
            u.gat.dsp[rloc][qh] = ds;
        }
    }
    // FM 1st order (th=0 waves)
    if (nhalf == 0) {
        float fmsum = 0.f;
        for (int f = qh; f < NF; f += 4)
            fmsum += fm1[(size_t)f * NV + idxp[f]];
        u.gat.fmp[rloc][qh] = fmsum;
    }
    // FM 2nd-order partials + convert + write frags to LDS
    {
        float s8[8] = {0.f,0.f,0.f,0.f,0.f,0.f,0.f,0.f};
        float ssacc = 0.f;
        #pragma unroll
        for (int t = 0; t < 7; ++t) {
            if (t < ntile) {
                #pragma unroll
                for (int j = 0; j < 8; ++j) { s8[j] += v[t][j]; ssacc += v[t][j] * v[t][j]; }
            }
        }
        #pragma unroll
        for (int j = 0; j < 8; ++j) u.gat.sfm[nhalf][rloc][qh][j] = s8[j];
        u.gat.ssq[nhalf][rloc][qh] = ssacc;
        #pragma unroll
        for (int t = 0; t < 7; ++t) {
            if (t < ntile) {
                int kt = tbase + t;
                unsigned short o[8];
                #pragma unroll
                for (int j = 0; j < 8; ++j) o[j] = f2bf(v[t][j]);
                *(uint4v*)&a_s[(size_t)(((kt * 4 + qh) * 64) + rloc) * 8] = *(uint4v*)o;
            }
        }
    }
    __syncthreads();   // gather + W tile 0 + FM partials all visible

    // ---- FM finalize: 8 threads per row, 2 k's each ----
    {
        int row = tid >> 3, sub = tid & 7;
        float part = 0.f;
        #pragma unroll
        for (int kk = 0; kk < 2; ++kk) {
            int k = sub * 2 + kk;
            int j = k & 7;
            int q0 = (k < 8) ? 0 : 1;
            float s_tot = u.gat.sfm[0][row][q0][j] + u.gat.sfm[0][row][q0 + 2][j]
                        + u.gat.sfm[1][row][q0][j] + u.gat.sfm[1][row][q0 + 2][j];
            part += s_tot * s_tot;
        }
        part += __shfl_xor(part, 1, 64);
        part += __shfl_xor(part, 2, 64);
        part += __shfl_xor(part, 4, 64);
        if (sub == 0) {
            float ssqt = 0.f;
            #pragma unroll
            for (int th = 0; th < 2; ++th)
                #pragma unroll
                for (int q = 0; q < 4; ++q) ssqt += u.gat.ssq[th][row][q];
            float fmt = u.gat.fmp[row][0] + u.gat.fmp[row][1]
                      + u.gat.fmp[row][2] + u.gat.fmp[row][3];
            float dt = u.gat.dsp[row][0] + u.gat.dsp[row][1];
            base[m0 + row] = 0.5f * (part - ssqt) + fmt + dt + bd[0];
        }
    }

    // ---- phase B: K-loop, A from LDS, W dbuf DMA ----
    f32x4 acc[13];
    #pragma unroll
    for (int i = 0; i < 13; ++i) acc[i] = f32x4{0.f, 0.f, 0.f, 0.f};

    #pragma unroll
    for (int kt = 0; kt < 14; ++kt) {
        if (kt + 1 < 14 && wv < 7) stage(kt + 1, (kt + 1) & 1);
        short8 af;
        if (kt < 13)
            af = *(const short8*)&a_s[(size_t)(((kt * 4 + qh) * 64) + rloc) * 8];
        else
            af = af13;
        const unsigned short* bb = &b_s[kt & 1][(size_t)(qh * 448 + c0 + l15) * 8];
        #pragma unroll
        for (int nn = 0; nn < 13; ++nn) {
            if (nn < NFRAG) {
                short8 bf = *(const short8*)(bb + nn * 128);
                acc[nn] = __builtin_amdgcn_mfma_f32_16x16x32_bf16(af, bf, acc[nn], 0, 0, 0);
            }
        }
        __syncthreads();
    }

    // ---- epilogue: +bias, bf16 store, fp32 column stats ----
    #pragma unroll
    for (int nn = 0; nn < 13; ++nn) {
        if (nn < NFRAG) {
            int col = c0 + nn * 16 + l15;
            float bv = bias[col];
            float ps = 0.f, pq = 0.f;
            #pragma unroll
            for (int q = 0; q < 4; ++q) {
                float val = acc[nn][q] + bv;
                ps += val; pq += val * val;
                Z[(size_t)(m0 + rowgrp * 16 + qh * 4 + q) * ZPAD + col] = f2bf(val);
            }
            ps += __shfl_xor(ps, 16, 64); ps += __shfl_xor(ps, 32, 64);
            pq += __shfl_xor(pq, 16, 64); pq += __shfl_xor(pq, 32, 64);
            if (lane < 16) { u.red.S[rowgrp][col] = ps; u.red.Q[rowgrp][col] = pq; }
        }
    }
    if (nhalf == 1) {   // zero-pad cols 400..415 for GEMM2's A reads
        int col = NH + l15;
        #pragma unroll
        for (int q = 0; q < 4; ++q)
            Z[(size_t)(m0 + rowgrp * 16 + qh * 4 + q) * ZPAD + col] = 0;
    }
    __syncthreads();
    for (int c = tid; c < NH; c += 512) {
        float s = u.red.S[0][c] + u.red.S[1][c] + u.red.S[2][c] + u.red.S[3][c];
        float q = u.red.Q[0][c] + u.red.Q[1][c] + u.red.Q[2][c] + u.red.Q[3][c];
        atomicAdd(&gsum[c], s);
        atomicAdd(&gsq[c], q);
    }
}

// =====================================================================
// K2: MFMA GEMM with fused BN1+ReLU on A, 2-phase gload_lds W staging.
// =====================================================================
__global__ __launch_bounds__(512, 2) void mfma_gemm2(
    const unsigned short* __restrict__ A,
    const unsigned short* __restrict__ Wst,
    const float* __restrict__ bias,
    const float* __restrict__ gsumIn, const float* __restrict__ gsqIn,
    const float* __restrict__ g, const float* __restrict__ be,
    unsigned short* __restrict__ Z,
    float* __restrict__ gsum, float* __restrict__ gsq)
{
    __shared__ unsigned short b_s[2][14336];
    __shared__ float sredS[4][416];
    __shared__ float sredQ[4][416];
    __shared__ float alpha_s[416], beta_s[416];

    const int tid = threadIdx.x;
    const int lane = tid & 63;
    const int wv = tid >> 6;
    const int rowgrp = wv & 3;
    const int nhalf = wv >> 2;
    const int l15 = lane & 15;
    const int qh = lane >> 4;
    const int m0 = blockIdx.x * 64;
    const int arow = m0 + rowgrp * 16 + l15;
    const int c0 = nhalf * 208;
    const int NFRAG = nhalf ? 12 : 13;

    for (int c = tid; c < ZPAD; c += 512) {
        float a = 0.f, b = 0.f;
        if (c < NH) {
            float mean = gsumIn[c] * (1.f / B_ROWS);
            float var  = gsqIn[c] * (1.f / B_ROWS) - mean * mean;
            a = g[c] * rsqrtf(var + EPS);
            b = be[c] - mean * a;
        }
        alpha_s[c] = a; beta_s[c] = b;
    }

    f32x4 acc[13];
    #pragma unroll
    for (int i = 0; i < 13; ++i) acc[i] = f32x4{0.f, 0.f, 0.f, 0.f};

    auto stage = [&](int kt, int buf) {
        #pragma unroll
        for (int i = 0; i < 4; ++i) {
            int cchunk = wv * 256 + i * 64 + lane;
            gload_lds16(Wst + (size_t)kt * 14336 + (size_t)cchunk * 8,
                        &b_s[buf][(size_t)(wv * 256 + i * 64) * 8]);
        }
    };

    if (wv < 7) stage(0, 0);
    short8 af_next = *(const short8*)(A + (size_t)arow * ZPAD + qh * 8);
    __syncthreads();

    for (int kt = 0; kt < 13; ++kt) {
        if (kt + 1 < 13 && wv < 7) stage(kt + 1, (kt + 1) & 1);
        short8 af = af_next;
        if (kt + 1 < 13)
            af_next = *(const short8*)(A + (size_t)arow * ZPAD + (kt + 1) * 32 + qh * 8);
        int k0 = kt * 32 + qh * 8;
        #pragma unroll
        for (int j = 0; j < 8; ++j) {
            float f = bf2f((unsigned short)af[j]);
            f = fmaxf(0.f, alpha_s[k0 + j] * f + beta_s[k0 + j]);
            af[j] = (short)f2bf(f);
        }
        const unsigned short* bb = &b_s[kt & 1][(size_t)(qh * 448 + c0 + l15) * 8];
        #pragma unroll
        for (int nn = 0; nn < 13; ++nn) {
            if (nn < NFRAG) {
                short8 bf = *(const short8*)(bb + nn * 128);
                acc[nn] = __builtin_amdgcn_mfma_f32_16x16x32_bf16(af, bf, acc[nn], 0, 0, 0);
            }
        }
        __syncthreads();
    }

    #pragma unroll
    for (int nn = 0; nn < 13; ++nn) {
        if (nn < NFRAG) {
            int col = c0 + nn * 16 + l15;
            float bv = bias[col];
            float ps = 0.f, pq = 0.f;
            #pragma unroll
            for (int q = 0; q < 4; ++q) {
                float v = acc[nn][q] + bv;
                ps += v; pq += v * v;
                Z[(size_t)(m0 + rowgrp * 16 + qh * 4 + q) * ZPAD + col] = f2bf(v);
            }
            ps += __shfl_xor(ps, 16, 64); ps += __shfl_xor(ps, 32, 64);
            pq += __shfl_xor(pq, 16, 64); pq += __shfl_xor(pq, 32, 64);
            if (lane < 16) { sredS[rowgrp][col] = ps; sredQ[rowgrp][col] = pq; }
        }
    }
    __syncthreads();
    for (int c = tid; c < NH; c += 512) {
        float s = sredS[0][c] + sredS[1][c] + sredS[2][c] + sredS[3][c];
        float q = sredQ[0][c] + sredQ[1][c] + sredQ[2][c] + sredQ[3][c];
        atomicAdd(&gsum[c], s);
        atomicAdd(&gsq[c], q);
    }
}

// =====================================================================
// final: finalize BN2 in-block, then out[r] = base[r] + relu(.)·W3 + b3
// =====================================================================
__global__ __launch_bounds__(256) void final_kernel(
    const unsigned short* __restrict__ Z2,
    const float* __restrict__ gsum2, const float* __restrict__ gsq2,
    const float* __restrict__ g2, const float* __restrict__ be2,
    const float* __restrict__ W3, const float* __restrict__ b3,
    const float* __restrict__ base, float* __restrict__ out)
{
    __shared__ float a2s[NH], b2s[NH], w3s[NH];
    int tid = threadIdx.x;
    for (int c = tid; c < NH; c += 256) {
        float mean = gsum2[c] * (1.f / B_ROWS);
        float var  = gsq2[c] * (1.f / B_ROWS) - mean * mean;
        float a = g2[c] * rsqrtf(var + EPS);
        a2s[c] = a;
        b2s[c] = be2[c] - mean * a;
        w3s[c] = W3[c];
    }
    __syncthreads();
    int lane = tid & 63;
    int wv = tid >> 6;
    bool act = lane < 50;
    int cb = lane * 8;
    float al[8], bb[8], w3[8];
    #pragma unroll
    for (int j = 0; j < 8; ++j) {
        al[j] = act ? a2s[cb + j] : 0.f;
        bb[j] = act ? b2s[cb + j] : 0.f;
        w3[j] = act ? w3s[cb + j] : 0.f;
    }
    int r0 = blockIdx.x * 32 + wv * 8;
    float bias3 = b3[0];
    for (int t = 0; t < 8; t += 2) {
        int r = r0 + t;
        float acc0 = 0.f, acc1 = 0.f;
        if (act) {
            short8 z0 = *(const short8*)(Z2 + (size_t)r * ZPAD + cb);
            short8 z1 = *(const short8*)(Z2 + (size_t)(r + 1) * ZPAD + cb);
            #pragma unroll
            for (int j = 0; j < 8; ++j) {
                acc0 += fmaxf(0.f, al[j] * bf2f((unsigned short)z0[j]) + bb[j]) * w3[j];
                acc1 += fmaxf(0.f, al[j] * bf2f((unsigned short)z1[j]) + bb[j]) * w3[j];
            }
        }
        #pragma unroll
        for (int off = 32; off; off >>= 1) {
            acc0 += __shfl_xor(acc0, off, 64);
            acc1 += __shfl_xor(acc1, off, 64);
        }
        if (lane == 0) out[r] = base[r] + acc0 + bias3;
        if (lane == 1) out[r + 1] = base[r + 1] + acc1 + bias3;
    }
}

// =====================================================================
extern "C" void kernel_launch(void* const* d_in, const int* in_sizes, int n_in,
                              void* d_out, int out_size, void* d_ws, size_t ws_size,
                              hipStream_t stream)
{
    const int*   Xcat = (const int*)d_in[0];
    const float* Xd   = (const float*)d_in[1];
    const float* fm1  = (const float*)d_in[2];
    const float* emb  = (const float*)d_in[3];
    const float* Wd   = (const float*)d_in[4];
    const float* bd   = (const float*)d_in[5];
    const float* W1   = (const float*)d_in[6];
    const float* b1   = (const float*)d_in[7];
    const float* g1   = (const float*)d_in[8];
    const float* be1  = (const float*)d_in[9];
    const float* W2   = (const float*)d_in[10];
    const float* b2   = (const float*)d_in[11];
    const float* g2   = (const float*)d_in[12];
    const float* be2  = (const float*)d_in[13];
    const float* W3   = (const float*)d_in[14];
    const float* b3   = (const float*)d_in[15];

    char* ws = (char*)d_ws;
    unsigned short* Z1  = (unsigned short*)(ws + Z1_OFF);
    unsigned short* Z2  = (unsigned short*)(ws + Z2_OFF);
    unsigned short* W1s = (unsigned short*)(ws + W1S_OFF);
    unsigned short* W2s = (unsigned short*)(ws + W2S_OFF);
    float* base = (float*)(ws + BASE_OFF);
    float* st   = (float*)(ws + ST_OFF);
    float* gsum1 = st;          float* gsq1 = st + 416;
    float* gsum2 = st + 832;    float* gsq2 = st + 1248;
    float* out = (float*)d_out;

    // 1: stage W1/W2 + zero stats
    prep_w<<<95, 512, 0, stream>>>(W1, W2, W1s, W2s, st);

    // 2: fused gather + FM + GEMM1
    gemm1_fused<<<256, 512, 0, stream>>>(Xcat, Xd, fm1, emb, Wd, bd,
                                         W1s, b1, Z1, base, gsum1, gsq1);

    // 3: Z2 = relu(bn1(Z1)) @ W2 + b2, stats2
    mfma_gemm2<<<256, 512, 0, stream>>>(Z1, W2s, b2, gsum1, gsq1, g1, be1,
                                        Z2, gsum2, gsq2);

    // 4: out = base + relu(bn2(Z2))·W3 + b3
    final_kernel<<<512, 256, 0, stream>>>(Z2, gsum2, gsq2, g2, be2, W3, b3, base, out);
}